// Round 7
// baseline (670.395 us; speedup 1.0000x reference)
//
#include <hip/hip_runtime.h>

#define N_NODES 100000
#define D_IN 128
#define D_OUT 256            // OUT_CH * HEADS
#define NBLKN ((N_NODES + 255) / 256)   // 391 node-blocks for scans
#define EBLK 2048            // grid-stride blocks for edge passes

typedef __attribute__((ext_vector_type(8))) short short8_t;  // 8 bf16
typedef __attribute__((ext_vector_type(4))) float f32x4;

__device__ inline unsigned short f2bf_rne(float f) {
    unsigned u = __float_as_uint(f);
    u += 0x7fffu + ((u >> 16) & 1u);
    return (unsigned short)(u >> 16);
}

// ---------------------------------------------------------------------------
// x (fp32) -> xb (bf16 as ushort)
// ---------------------------------------------------------------------------
__global__ __launch_bounds__(256) void convert_kernel(
    const float* __restrict__ x, ushort* __restrict__ xb, int n4)
{
    int i = blockIdx.x * 256 + threadIdx.x;
    if (i < n4) {
        float4 v = ((const float4*)x)[i];
        ushort4 r;
        r.x = f2bf_rne(v.x); r.y = f2bf_rne(v.y);
        r.z = f2bf_rne(v.z); r.w = f2bf_rne(v.w);
        ((ushort4*)xb)[i] = r;
    }
}

// ---------------------------------------------------------------------------
// W (fp32 [128][256]) -> wfrag: MFMA B-fragment order, bf16.
// frag index fi = ks*16+nt (ks: K-step of 32, nt: 16-col tile).
// lane l, elem e  <->  B[k][n], k = ks*32 + (l>>4)*8 + e, n = nt*16 + (l&15).
// ---------------------------------------------------------------------------
__global__ __launch_bounds__(256) void wfrag_kernel(
    const float* __restrict__ W, short8_t* __restrict__ wfrag)
{
    int tid  = blockIdx.x * 256 + threadIdx.x;   // 4096 frags total
    int lane = tid & 63;
    int fi   = tid >> 6;                          // 0..63
    int ks   = fi >> 4, nt = fi & 15;
    int k0   = ks * 32 + (lane >> 4) * 8;
    int col  = nt * 16 + (lane & 15);
    short8_t v;
    #pragma unroll
    for (int e = 0; e < 8; e++)
        v[e] = (short)f2bf_rne(W[(size_t)(k0 + e) * D_OUT + col]);
    wfrag[tid] = v;
}

// ---------------------------------------------------------------------------
// CSR build pass 0: zero the degree array
// ---------------------------------------------------------------------------
__global__ __launch_bounds__(256) void zero_deg(int* __restrict__ deg)
{
    int i = blockIdx.x * 256 + threadIdx.x;
    if (i < N_NODES) deg[i] = 0;
}

// ---------------------------------------------------------------------------
// CSR build pass 1: deg[dst]++ via global atomics (grid-stride)
// ---------------------------------------------------------------------------
__global__ __launch_bounds__(256) void count_deg(
    const int* __restrict__ dst, int* __restrict__ deg, int E)
{
    int stride = gridDim.x * 256;
    for (int i = blockIdx.x * 256 + threadIdx.x; i < E; i += stride)
        atomicAdd(&deg[dst[i]], 1);
}

// ---------------------------------------------------------------------------
// CSR build pass 2a: per-256-node-block exclusive scan of deg -> offs
// (partial, block-local); bsum[b] = block total.
// ---------------------------------------------------------------------------
__global__ __launch_bounds__(256) void scanA(
    const int* __restrict__ deg, int* __restrict__ offs, int* __restrict__ bsum)
{
    __shared__ int wsum[4];
    int b = blockIdx.x, t = threadIdx.x, lane = t & 63, w = t >> 6;
    int n = b * 256 + t;
    int v = (n < N_NODES) ? deg[n] : 0;
    int s = v;
    #pragma unroll
    for (int d = 1; d < 64; d <<= 1) {
        int u = __shfl_up(s, d);
        if (lane >= d) s += u;
    }
    if (lane == 63) wsum[w] = s;
    __syncthreads();
    int wo = 0;
    for (int j = 0; j < w; j++) wo += wsum[j];
    if (n < N_NODES) offs[n] = wo + s - v;
    if (t == 255) {
        int tot = 0;
        for (int j = 0; j < 4; j++) tot += wsum[j];
        bsum[b] = tot;
    }
}

// ---------------------------------------------------------------------------
// CSR build pass 2b: exclusive scan of bsum[NBLKN] -> bbase (1 block,
// 2 entries/thread, guarded)
// ---------------------------------------------------------------------------
__global__ __launch_bounds__(256) void scanB(
    const int* __restrict__ bsum, int* __restrict__ bbase)
{
    __shared__ int wsum[4];
    int t = threadIdx.x, lane = t & 63, w = t >> 6;
    int i0 = t * 2;
    int a0 = (i0     < NBLKN) ? bsum[i0]     : 0;
    int a1 = (i0 + 1 < NBLKN) ? bsum[i0 + 1] : 0;
    int v = a0 + a1;
    int s = v;
    #pragma unroll
    for (int d = 1; d < 64; d <<= 1) {
        int u = __shfl_up(s, d);
        if (lane >= d) s += u;
    }
    if (lane == 63) wsum[w] = s;
    __syncthreads();
    int wo = 0;
    for (int j = 0; j < w; j++) wo += wsum[j];
    int excl = wo + s - v;
    if (i0     < NBLKN) bbase[i0]     = excl;
    if (i0 + 1 < NBLKN) bbase[i0 + 1] = excl + a0;
}

// ---------------------------------------------------------------------------
// CSR build pass 2c: offs += bbase[block]; cur = offs (scatter cursors)
// ---------------------------------------------------------------------------
__global__ __launch_bounds__(256) void scanC(
    int* __restrict__ offs, const int* __restrict__ bbase, int* __restrict__ cur)
{
    int b = blockIdx.x, t = threadIdx.x;
    int n = b * 256 + t;
    if (n < N_NODES) {
        int o = offs[n] + bbase[b];
        offs[n] = o;
        cur[n]  = o;
    }
}

// ---------------------------------------------------------------------------
// CSR build pass 3: csr[atomicAdd(&cur[dst],1)] = src  (grid-stride)
// ---------------------------------------------------------------------------
__global__ __launch_bounds__(256) void scatter_csr(
    const int* __restrict__ src, const int* __restrict__ dst,
    int* __restrict__ cur, int* __restrict__ csr, int E)
{
    int stride = gridDim.x * 256;
    for (int i = blockIdx.x * 256 + threadIdx.x; i < E; i += stride) {
        int d = dst[i];
        int pos = atomicAdd(&cur[d], 1);
        csr[pos] = src[i];
    }
}

// ---------------------------------------------------------------------------
// Fused gather-aggregate + MFMA linear (round-5-verified, verbatim).
// Gather: readlane -> SGPR row base. h packed to bf16 in LDS with XOR
// swizzle (byte ^= (row&7)<<4). Matmul: M=16 x K=128 x N=256 via
// mfma_f32_16x16x32_bf16; wave w owns 16-col tiles w*4..w*4+3.
// C/D mapping (m89-verified): col = lane&15, row = (lane>>4)*4 + reg.
// ---------------------------------------------------------------------------
template <bool USE_BF16>
__global__ __launch_bounds__(256) void fused_kernel(
    const float* __restrict__ x,
    const ushort* __restrict__ xb,
    const int* __restrict__ offs,
    const int* __restrict__ deg,
    const int* __restrict__ sorted_src,
    const short8_t* __restrict__ wfrag,
    const float* __restrict__ b,
    float* __restrict__ out)
{
    __shared__ __align__(16) ushort shb[16 * D_IN];   // 4 KB bf16 h, swizzled

    int n0   = blockIdx.x * 16;
    int t    = threadIdx.x;
    int lane = t & 63;
    int w    = t >> 6;

    for (int nn = 0; nn < 4; nn++) {
        int nl = w * 4 + nn;
        int n  = n0 + nl;
        int start = offs[n];
        int d     = deg[n];
        float accx = 0.0f, accy = 0.0f;
        for (int base = 0; base < d; base += 64) {
            int m = d - base; if (m > 64) m = 64;
            int id = (lane < m) ? sorted_src[start + base + lane] : 0;
            int j = 0;
            for (; j + 4 <= m; j += 4) {
                int s0 = __builtin_amdgcn_readlane(id, j);
                int s1 = __builtin_amdgcn_readlane(id, j + 1);
                int s2 = __builtin_amdgcn_readlane(id, j + 2);
                int s3 = __builtin_amdgcn_readlane(id, j + 3);
                if (USE_BF16) {
                    ushort2 u0 = ((const ushort2*)(xb + (size_t)s0 * D_IN))[lane];
                    ushort2 u1 = ((const ushort2*)(xb + (size_t)s1 * D_IN))[lane];
                    ushort2 u2 = ((const ushort2*)(xb + (size_t)s2 * D_IN))[lane];
                    ushort2 u3 = ((const ushort2*)(xb + (size_t)s3 * D_IN))[lane];
                    accx += __uint_as_float((unsigned)u0.x << 16)
                          + __uint_as_float((unsigned)u1.x << 16)
                          + __uint_as_float((unsigned)u2.x << 16)
                          + __uint_as_float((unsigned)u3.x << 16);
                    accy += __uint_as_float((unsigned)u0.y << 16)
                          + __uint_as_float((unsigned)u1.y << 16)
                          + __uint_as_float((unsigned)u2.y << 16)
                          + __uint_as_float((unsigned)u3.y << 16);
                } else {
                    float2 v0 = ((const float2*)(x + (size_t)s0 * D_IN))[lane];
                    float2 v1 = ((const float2*)(x + (size_t)s1 * D_IN))[lane];
                    float2 v2 = ((const float2*)(x + (size_t)s2 * D_IN))[lane];
                    float2 v3 = ((const float2*)(x + (size_t)s3 * D_IN))[lane];
                    accx += v0.x + v1.x + v2.x + v3.x;
                    accy += v0.y + v1.y + v2.y + v3.y;
                }
            }
            for (; j < m; j++) {
                int s0 = __builtin_amdgcn_readlane(id, j);
                if (USE_BF16) {
                    ushort2 u0 = ((const ushort2*)(xb + (size_t)s0 * D_IN))[lane];
                    accx += __uint_as_float((unsigned)u0.x << 16);
                    accy += __uint_as_float((unsigned)u0.y << 16);
                } else {
                    float2 v0 = ((const float2*)(x + (size_t)s0 * D_IN))[lane];
                    accx += v0.x; accy += v0.y;
                }
            }
        }
        float invc = 1.0f / ((float)d + 1e-8f);
        float2 xv = ((const float2*)(x + (size_t)n * D_IN))[lane];
        float hx = xv.x + accx * invc;
        float hy = xv.y + accy * invc;
        // dims (2*lane, 2*lane+1) of row nl, bf16-packed, swizzled store
        unsigned hp = ((unsigned)f2bf_rne(hy) << 16) | (unsigned)f2bf_rne(hx);
        unsigned byteoff = ((unsigned)(nl * 256 + lane * 4)) ^ (((unsigned)nl & 7u) << 4);
        *(unsigned*)((char*)shb + byteoff) = hp;
    }
    __syncthreads();

    // ---- MFMA epilogue ----
    const int r  = lane & 15;
    const int hi = lane >> 4;

    // A-frags: lane l holds h[r][ks*32 + hi*8 .. +8]  (one b128 per ks)
    short8_t afrag[4];
    #pragma unroll
    for (int ks = 0; ks < 4; ks++) {
        unsigned aoff = ((unsigned)(r * 256 + ks * 64 + hi * 16)) ^ (((unsigned)r & 7u) << 4);
        afrag[ks] = *(const short8_t*)((const char*)shb + aoff);
    }

    f32x4 zero = {0.0f, 0.0f, 0.0f, 0.0f};
    f32x4 acc0 = zero, acc1 = zero, acc2 = zero, acc3 = zero;
    const int nt0 = w * 4;
    #pragma unroll
    for (int ks = 0; ks < 4; ks++) {
        short8_t b0 = wfrag[(ks * 16 + nt0    ) * 64 + lane];
        short8_t b1 = wfrag[(ks * 16 + nt0 + 1) * 64 + lane];
        short8_t b2 = wfrag[(ks * 16 + nt0 + 2) * 64 + lane];
        short8_t b3 = wfrag[(ks * 16 + nt0 + 3) * 64 + lane];
        acc0 = __builtin_amdgcn_mfma_f32_16x16x32_bf16(afrag[ks], b0, acc0, 0, 0, 0);
        acc1 = __builtin_amdgcn_mfma_f32_16x16x32_bf16(afrag[ks], b1, acc1, 0, 0, 0);
        acc2 = __builtin_amdgcn_mfma_f32_16x16x32_bf16(afrag[ks], b2, acc2, 0, 0, 0);
        acc3 = __builtin_amdgcn_mfma_f32_16x16x32_bf16(afrag[ks], b3, acc3, 0, 0, 0);
    }

    // Store: D col = r (within tile), row m = hi*4 + reg
    #pragma unroll
    for (int nt = 0; nt < 4; nt++) {
        f32x4 a = (nt == 0) ? acc0 : (nt == 1) ? acc1 : (nt == 2) ? acc2 : acc3;
        int col = (nt0 + nt) * 16 + r;
        float bias = b[col];
        #pragma unroll
        for (int reg = 0; reg < 4; reg++) {
            int node = n0 + hi * 4 + reg;
            out[(size_t)node * D_OUT + col] = a[reg] + bias;
        }
    }
}

extern "C" void kernel_launch(void* const* d_in, const int* in_sizes, int n_in,
                              void* d_out, int out_size, void* d_ws, size_t ws_size,
                              hipStream_t stream)
{
    const float* x  = (const float*)d_in[0];
    const int*   ei = (const int*)d_in[1];   // [2,E] int32: row0=src, row1=dst
    const float* W  = (const float*)d_in[2];
    const float* b  = (const float*)d_in[3];
    float*       out = (float*)d_out;

    const int E = in_sizes[1] / 2;
    const int* src = ei;
    const int* dst = ei + E;

    const size_t xb_bytes  = (size_t)N_NODES * D_IN * 2;     // 25.6 MB
    const size_t csr_b     = (size_t)E * 4;                  // 12.8 MB
    const size_t nodes_b   = (size_t)N_NODES * 4;            // 400 KB each
    const size_t bsum_b    = (size_t)512 * 4;                // 2 KB each
    const size_t wf_b      = (size_t)4096 * 16;              // 64 KB
    const size_t need_bf16 = xb_bytes + csr_b + 3 * nodes_b + 2 * bsum_b + wf_b;
    const bool use_bf16 = (ws_size >= need_bf16);

    char* p = (char*)d_ws;
    ushort* xb = nullptr;
    if (use_bf16) { xb = (ushort*)p; p += xb_bytes; }
    int* csr   = (int*)p;  p += csr_b;
    int* deg   = (int*)p;  p += nodes_b;
    int* offs  = (int*)p;  p += nodes_b;
    int* cur   = (int*)p;  p += nodes_b;
    int* bsum  = (int*)p;  p += bsum_b;
    int* bbase = (int*)p;  p += bsum_b;
    short8_t* wfrag = (short8_t*)p;

    if (use_bf16) {
        int n4 = N_NODES * D_IN / 4;
        convert_kernel<<<dim3((n4 + 255) / 256), dim3(256), 0, stream>>>(x, xb, n4);
    }
    wfrag_kernel<<<dim3(16), dim3(256), 0, stream>>>(W, wfrag);

    zero_deg   <<<dim3(NBLKN), dim3(256), 0, stream>>>(deg);
    count_deg  <<<dim3(EBLK),  dim3(256), 0, stream>>>(dst, deg, E);
    scanA      <<<dim3(NBLKN), dim3(256), 0, stream>>>(deg, offs, bsum);
    scanB      <<<dim3(1),     dim3(256), 0, stream>>>(bsum, bbase);
    scanC      <<<dim3(NBLKN), dim3(256), 0, stream>>>(offs, bbase, cur);
    scatter_csr<<<dim3(EBLK),  dim3(256), 0, stream>>>(src, dst, cur, csr, E);

    if (use_bf16)
        fused_kernel<true><<<dim3(N_NODES / 16), dim3(256), 0, stream>>>(
            x, xb, offs, deg, csr, wfrag, b, out);
    else
        fused_kernel<false><<<dim3(N_NODES / 16), dim3(256), 0, stream>>>(
            x, xb, offs, deg, csr, wfrag, b, out);
}

// Round 8
// 405.771 us; speedup vs baseline: 1.6522x; 1.6522x over previous
//
#include <hip/hip_runtime.h>

#define N_NODES 100000
#define D_IN 128
#define D_OUT 256            // OUT_CH * HEADS
#define NBLK 256             // coarse-pass blocks (1/CU)
#define NBKT 256             // bucket array size (196 used)
#define BSH  9               // bucket = dst >> 9  (512 nodes / bucket)
#define BNODES 512
#define NBUCKETS ((N_NODES + BNODES - 1) / BNODES)   // 196
#define CAP  19456           // max edges/bucket staged in LDS (mean 16384, +24 sigma)

typedef __attribute__((ext_vector_type(8))) short short8_t;  // 8 bf16
typedef __attribute__((ext_vector_type(4))) float f32x4;

__device__ inline unsigned short f2bf_rne(float f) {
    unsigned u = __float_as_uint(f);
    u += 0x7fffu + ((u >> 16) & 1u);
    return (unsigned short)(u >> 16);
}

// ---------------------------------------------------------------------------
// x (fp32) -> xb (bf16 as ushort)
// ---------------------------------------------------------------------------
__global__ __launch_bounds__(256) void convert_kernel(
    const float* __restrict__ x, ushort* __restrict__ xb, int n4)
{
    int i = blockIdx.x * 256 + threadIdx.x;
    if (i < n4) {
        float4 v = ((const float4*)x)[i];
        ushort4 r;
        r.x = f2bf_rne(v.x); r.y = f2bf_rne(v.y);
        r.z = f2bf_rne(v.z); r.w = f2bf_rne(v.w);
        ((ushort4*)xb)[i] = r;
    }
}

// ---------------------------------------------------------------------------
// W (fp32 [128][256]) -> wfrag: MFMA B-fragment order, bf16.
// frag index fi = ks*16+nt (ks: K-step of 32, nt: 16-col tile).
// lane l, elem e  <->  B[k][n], k = ks*32 + (l>>4)*8 + e, n = nt*16 + (l&15).
// ---------------------------------------------------------------------------
__global__ __launch_bounds__(256) void wfrag_kernel(
    const float* __restrict__ W, short8_t* __restrict__ wfrag)
{
    int tid  = blockIdx.x * 256 + threadIdx.x;   // 4096 frags total
    int lane = tid & 63;
    int fi   = tid >> 6;                          // 0..63
    int ks   = fi >> 4, nt = fi & 15;
    int k0   = ks * 32 + (lane >> 4) * 8;
    int col  = nt * 16 + (lane & 15);
    short8_t v;
    #pragma unroll
    for (int e = 0; e < 8; e++)
        v[e] = (short)f2bf_rne(W[(size_t)(k0 + e) * D_OUT + col]);
    wfrag[tid] = v;
}

// ---------------------------------------------------------------------------
// Coarse pass 1: per-block LDS histogram of 196 buckets
// ---------------------------------------------------------------------------
__global__ __launch_bounds__(256) void binA_hist(
    const int* __restrict__ dst, int* __restrict__ blockHist, int E, int chunk)
{
    __shared__ int h[NBKT];
    int b = blockIdx.x, t = threadIdx.x;
    h[t] = 0;
    __syncthreads();
    int e0 = b * chunk, e1 = min(e0 + chunk, E);
    for (int e = e0 + t; e < e1; e += 256)
        atomicAdd(&h[dst[e] >> BSH], 1);
    __syncthreads();
    blockHist[b * NBKT + t] = h[t];
}

// ---------------------------------------------------------------------------
// Coarse pass 2a: per-bucket exclusive scan over NBLK=256 blocks, in place;
// bucketTotal[bucket] = column sum.
// ---------------------------------------------------------------------------
__global__ __launch_bounds__(256) void binA_scan(
    int* __restrict__ blockHist, int* __restrict__ bucketTotal)
{
    __shared__ int wsum[4];
    int bucket = blockIdx.x;
    int t = threadIdx.x, lane = t & 63, w = t >> 6;
    int v = blockHist[t * NBKT + bucket];
    int s = v;
    #pragma unroll
    for (int d = 1; d < 64; d <<= 1) {
        int u = __shfl_up(s, d);
        if (lane >= d) s += u;
    }
    if (lane == 63) wsum[w] = s;
    __syncthreads();
    int wo = 0;
    for (int j = 0; j < w; j++) wo += wsum[j];
    blockHist[t * NBKT + bucket] = wo + s - v;
    if (t == 255) {
        int tot = 0;
        for (int j = 0; j < 4; j++) tot += wsum[j];
        bucketTotal[bucket] = tot;
    }
}

// ---------------------------------------------------------------------------
// Coarse pass 2b: exclusive scan of bucketTotal[256] -> bucketBase[256]
// ---------------------------------------------------------------------------
__global__ __launch_bounds__(256) void binA_scanbase(
    const int* __restrict__ bucketTotal, int* __restrict__ bucketBase)
{
    __shared__ int wsum[4];
    int t = threadIdx.x, lane = t & 63, w = t >> 6;
    int v = bucketTotal[t];
    int s = v;
    #pragma unroll
    for (int d = 1; d < 64; d <<= 1) {
        int u = __shfl_up(s, d);
        if (lane >= d) s += u;
    }
    if (lane == 63) wsum[w] = s;
    __syncthreads();
    int wo = 0;
    for (int j = 0; j < w; j++) wo += wsum[j];
    bucketBase[t] = wo + s - v;
}

// ---------------------------------------------------------------------------
// Coarse pass 3: scatter packed (dstLocal<<17 | src) into bucket regions.
// Per-(block,bucket) runs are ~64 edges (256B) -> low cross-XCD line sharing.
// ---------------------------------------------------------------------------
__global__ __launch_bounds__(256) void binA_scatter(
    const int* __restrict__ src, const int* __restrict__ dst,
    const int* __restrict__ blockHist, const int* __restrict__ bucketBase,
    unsigned* __restrict__ pairs, int E, int chunk)
{
    __shared__ int offs[NBKT];
    int b = blockIdx.x, t = threadIdx.x;
    offs[t] = bucketBase[t] + blockHist[b * NBKT + t];
    __syncthreads();
    int e0 = b * chunk, e1 = min(e0 + chunk, E);
    for (int e = e0 + t; e < e1; e += 256) {
        int d = dst[e];
        int bin = d >> BSH;
        int pos = atomicAdd(&offs[bin], 1);
        pairs[pos] = ((unsigned)(d & (BNODES - 1)) << 17) | (unsigned)src[e];
    }
}

// ---------------------------------------------------------------------------
// Fine pass: per-bucket LDS counting sort (512-node buckets, ~80 KB LDS).
// Stages bucket edges in LDS, builds per-node deg/offs, rewrites sorted src
// IN PLACE over pairs. 2 bins per thread in the scan.
// ---------------------------------------------------------------------------
__global__ __launch_bounds__(256) void binB_sort(
    unsigned* __restrict__ pairs, const int* __restrict__ bucketBase,
    int* __restrict__ offs_g, int* __restrict__ deg_g)
{
    __shared__ unsigned stage[CAP];    // 76 KB
    __shared__ int hist[BNODES];
    __shared__ int rank[BNODES];
    __shared__ int wsum[4];

    int b = blockIdx.x, t = threadIdx.x, lane = t & 63, w = t >> 6;
    int e0 = bucketBase[b], e1 = bucketBase[b + 1];
    int cnt = e1 - e0;
    if (cnt > CAP) cnt = CAP;   // statistically unreachable (mean+24 sigma)

    hist[t] = 0; hist[t + 256] = 0;
    __syncthreads();

    for (int i = t; i < cnt; i += 256) {
        unsigned p = pairs[e0 + i];
        stage[i] = p;
        atomicAdd(&hist[p >> 17], 1);
    }
    __syncthreads();

    // scan 512 bins, 2 per thread
    int a0 = hist[t * 2], a1 = hist[t * 2 + 1];
    int v = a0 + a1;
    int s = v;
    #pragma unroll
    for (int d = 1; d < 64; d <<= 1) {
        int u = __shfl_up(s, d);
        if (lane >= d) s += u;
    }
    if (lane == 63) wsum[w] = s;
    __syncthreads();
    int wo = 0;
    for (int j = 0; j < w; j++) wo += wsum[j];
    int excl = wo + s - v;

    rank[t * 2]     = excl;
    rank[t * 2 + 1] = excl + a0;
    int node = (b << BSH) + t * 2;
    if (node < N_NODES) {
        offs_g[node] = e0 + excl;
        deg_g[node]  = a0;
    }
    if (node + 1 < N_NODES) {
        offs_g[node + 1] = e0 + excl + a0;
        deg_g[node + 1]  = a1;
    }
    __syncthreads();

    for (int i = t; i < cnt; i += 256) {
        unsigned p = stage[i];
        int pos = atomicAdd(&rank[p >> 17], 1);
        pairs[e0 + pos] = p & 0x1FFFFu;
    }
}

// ---------------------------------------------------------------------------
// Fused gather-aggregate + MFMA linear (round-5-verified, verbatim).
// ---------------------------------------------------------------------------
template <bool USE_BF16>
__global__ __launch_bounds__(256) void fused_kernel(
    const float* __restrict__ x,
    const ushort* __restrict__ xb,
    const int* __restrict__ offs,
    const int* __restrict__ deg,
    const int* __restrict__ sorted_src,
    const short8_t* __restrict__ wfrag,
    const float* __restrict__ b,
    float* __restrict__ out)
{
    __shared__ __align__(16) ushort shb[16 * D_IN];   // 4 KB bf16 h, swizzled

    int n0   = blockIdx.x * 16;
    int t    = threadIdx.x;
    int lane = t & 63;
    int w    = t >> 6;

    for (int nn = 0; nn < 4; nn++) {
        int nl = w * 4 + nn;
        int n  = n0 + nl;
        int start = offs[n];
        int d     = deg[n];
        float accx = 0.0f, accy = 0.0f;
        for (int base = 0; base < d; base += 64) {
            int m = d - base; if (m > 64) m = 64;
            int id = (lane < m) ? sorted_src[start + base + lane] : 0;
            int j = 0;
            for (; j + 4 <= m; j += 4) {
                int s0 = __builtin_amdgcn_readlane(id, j);
                int s1 = __builtin_amdgcn_readlane(id, j + 1);
                int s2 = __builtin_amdgcn_readlane(id, j + 2);
                int s3 = __builtin_amdgcn_readlane(id, j + 3);
                if (USE_BF16) {
                    ushort2 u0 = ((const ushort2*)(xb + (size_t)s0 * D_IN))[lane];
                    ushort2 u1 = ((const ushort2*)(xb + (size_t)s1 * D_IN))[lane];
                    ushort2 u2 = ((const ushort2*)(xb + (size_t)s2 * D_IN))[lane];
                    ushort2 u3 = ((const ushort2*)(xb + (size_t)s3 * D_IN))[lane];
                    accx += __uint_as_float((unsigned)u0.x << 16)
                          + __uint_as_float((unsigned)u1.x << 16)
                          + __uint_as_float((unsigned)u2.x << 16)
                          + __uint_as_float((unsigned)u3.x << 16);
                    accy += __uint_as_float((unsigned)u0.y << 16)
                          + __uint_as_float((unsigned)u1.y << 16)
                          + __uint_as_float((unsigned)u2.y << 16)
                          + __uint_as_float((unsigned)u3.y << 16);
                } else {
                    float2 v0 = ((const float2*)(x + (size_t)s0 * D_IN))[lane];
                    float2 v1 = ((const float2*)(x + (size_t)s1 * D_IN))[lane];
                    float2 v2 = ((const float2*)(x + (size_t)s2 * D_IN))[lane];
                    float2 v3 = ((const float2*)(x + (size_t)s3 * D_IN))[lane];
                    accx += v0.x + v1.x + v2.x + v3.x;
                    accy += v0.y + v1.y + v2.y + v3.y;
                }
            }
            for (; j < m; j++) {
                int s0 = __builtin_amdgcn_readlane(id, j);
                if (USE_BF16) {
                    ushort2 u0 = ((const ushort2*)(xb + (size_t)s0 * D_IN))[lane];
                    accx += __uint_as_float((unsigned)u0.x << 16);
                    accy += __uint_as_float((unsigned)u0.y << 16);
                } else {
                    float2 v0 = ((const float2*)(x + (size_t)s0 * D_IN))[lane];
                    accx += v0.x; accy += v0.y;
                }
            }
        }
        float invc = 1.0f / ((float)d + 1e-8f);
        float2 xv = ((const float2*)(x + (size_t)n * D_IN))[lane];
        float hx = xv.x + accx * invc;
        float hy = xv.y + accy * invc;
        unsigned hp = ((unsigned)f2bf_rne(hy) << 16) | (unsigned)f2bf_rne(hx);
        unsigned byteoff = ((unsigned)(nl * 256 + lane * 4)) ^ (((unsigned)nl & 7u) << 4);
        *(unsigned*)((char*)shb + byteoff) = hp;
    }
    __syncthreads();

    // ---- MFMA epilogue ----
    const int r  = lane & 15;
    const int hi = lane >> 4;

    short8_t afrag[4];
    #pragma unroll
    for (int ks = 0; ks < 4; ks++) {
        unsigned aoff = ((unsigned)(r * 256 + ks * 64 + hi * 16)) ^ (((unsigned)r & 7u) << 4);
        afrag[ks] = *(const short8_t*)((const char*)shb + aoff);
    }

    f32x4 zero = {0.0f, 0.0f, 0.0f, 0.0f};
    f32x4 acc0 = zero, acc1 = zero, acc2 = zero, acc3 = zero;
    const int nt0 = w * 4;
    #pragma unroll
    for (int ks = 0; ks < 4; ks++) {
        short8_t b0 = wfrag[(ks * 16 + nt0    ) * 64 + lane];
        short8_t b1 = wfrag[(ks * 16 + nt0 + 1) * 64 + lane];
        short8_t b2 = wfrag[(ks * 16 + nt0 + 2) * 64 + lane];
        short8_t b3 = wfrag[(ks * 16 + nt0 + 3) * 64 + lane];
        acc0 = __builtin_amdgcn_mfma_f32_16x16x32_bf16(afrag[ks], b0, acc0, 0, 0, 0);
        acc1 = __builtin_amdgcn_mfma_f32_16x16x32_bf16(afrag[ks], b1, acc1, 0, 0, 0);
        acc2 = __builtin_amdgcn_mfma_f32_16x16x32_bf16(afrag[ks], b2, acc2, 0, 0, 0);
        acc3 = __builtin_amdgcn_mfma_f32_16x16x32_bf16(afrag[ks], b3, acc3, 0, 0, 0);
    }

    #pragma unroll
    for (int nt = 0; nt < 4; nt++) {
        f32x4 a = (nt == 0) ? acc0 : (nt == 1) ? acc1 : (nt == 2) ? acc2 : acc3;
        int col = (nt0 + nt) * 16 + r;
        float bias = b[col];
        #pragma unroll
        for (int reg = 0; reg < 4; reg++) {
            int node = n0 + hi * 4 + reg;
            out[(size_t)node * D_OUT + col] = a[reg] + bias;
        }
    }
}

extern "C" void kernel_launch(void* const* d_in, const int* in_sizes, int n_in,
                              void* d_out, int out_size, void* d_ws, size_t ws_size,
                              hipStream_t stream)
{
    const float* x  = (const float*)d_in[0];
    const int*   ei = (const int*)d_in[1];   // [2,E] int32: row0=src, row1=dst
    const float* W  = (const float*)d_in[2];
    const float* b  = (const float*)d_in[3];
    float*       out = (float*)d_out;

    const int E = in_sizes[1] / 2;
    const int* src = ei;
    const int* dst = ei + E;
    const int chunk = (E + NBLK - 1) / NBLK;

    const size_t xb_bytes   = (size_t)N_NODES * D_IN * 2;     // 25.6 MB
    const size_t pairs_b    = (size_t)E * 4;                  // 12.8 MB
    const size_t bh_b       = (size_t)NBLK * NBKT * 4;        // 256 KB
    const size_t small_b    = (size_t)NBKT * 4;               // 1 KB each
    const size_t nodes_b    = (size_t)N_NODES * 4;            // 400 KB each
    const size_t wf_b       = (size_t)4096 * 16;              // 64 KB
    const size_t need_bf16  = xb_bytes + pairs_b + bh_b + 2 * small_b
                            + 2 * nodes_b + wf_b;             // ~39.5 MB
    const bool use_bf16 = (ws_size >= need_bf16);

    char* p = (char*)d_ws;
    ushort* xb = nullptr;
    if (use_bf16) { xb = (ushort*)p; p += xb_bytes; }
    unsigned* pairs  = (unsigned*)p;  p += pairs_b;
    int* blockHist   = (int*)p;       p += bh_b;
    int* bucketTotal = (int*)p;       p += small_b;
    int* bucketBase  = (int*)p;       p += small_b;
    int* offs        = (int*)p;       p += nodes_b;
    int* deg         = (int*)p;       p += nodes_b;
    short8_t* wfrag  = (short8_t*)p;

    if (use_bf16) {
        int n4 = N_NODES * D_IN / 4;
        convert_kernel<<<dim3((n4 + 255) / 256), dim3(256), 0, stream>>>(x, xb, n4);
    }
    wfrag_kernel<<<dim3(16), dim3(256), 0, stream>>>(W, wfrag);

    binA_hist    <<<dim3(NBLK), dim3(256), 0, stream>>>(dst, blockHist, E, chunk);
    binA_scan    <<<dim3(NBKT), dim3(256), 0, stream>>>(blockHist, bucketTotal);
    binA_scanbase<<<dim3(1),    dim3(256), 0, stream>>>(bucketTotal, bucketBase);
    binA_scatter <<<dim3(NBLK), dim3(256), 0, stream>>>(
        src, dst, blockHist, bucketBase, pairs, E, chunk);
    binB_sort    <<<dim3(NBUCKETS), dim3(256), 0, stream>>>(
        pairs, bucketBase, offs, deg);

    if (use_bf16)
        fused_kernel<true><<<dim3(N_NODES / 16), dim3(256), 0, stream>>>(
            x, xb, offs, deg, (const int*)pairs, wfrag, b, out);
    else
        fused_kernel<false><<<dim3(N_NODES / 16), dim3(256), 0, stream>>>(
            x, xb, offs, deg, (const int*)pairs, wfrag, b, out);
}